// Round 3
// baseline (512.702 us; speedup 1.0000x reference)
//
#include <hip/hip_runtime.h>

#define N_NODES 100000
#define T_P 12
#define C_H 32
#define E_EDGES 3200000

#define NPB 256                 // nodes per bucket (dst>>8)
#define NB 391                  // ceil(N/256)
#define NBP (NB * NPB)          // padded node count = 100096
#define NC 256                  // edge chunks
#define CE 12500                // edges per chunk (NC*CE == E)
#define K_DEG 4
#define K_AGG 2

// ws layout (4B units):
//  P:0(256) | start:256(392) | tot:648(392) | histo:1040(100096) | bp:101136(100096)
//  | degp:201232(4*100096) | dinv:601616(100096) | rec:701712(2*E uint2)
//  | aggp:7101712(2*100096*12)   -> total ~38.0 MB

__global__ void params_kernel(const float* __restrict__ wz, const float* __restrict__ bz,
                              const float* __restrict__ wh, const float* __restrict__ bh,
                              const float* __restrict__ lwz, const float* __restrict__ lbz,
                              const float* __restrict__ lwh, const float* __restrict__ lbh,
                              const float* __restrict__ att, float* __restrict__ P) {
    int o = threadIdx.x;
    if (o < C_H) {
        float az = 0.f, bzv = 0.f, ah = 0.f, bhv = 0.f;
        for (int c = 0; c < C_H; ++c) {
            float lz = lwz[o * 2 * C_H + c];
            float lh = lwh[o * 2 * C_H + c];
            az += wz[c] * lz;  bzv += bz[c] * lz;
            ah += wh[c] * lh;  bhv += bh[c] * lh;
        }
        P[16 + o]  = az;  P[48 + o]  = bzv + lbz[o];
        P[80 + o]  = ah;  P[112 + o] = bhv + lbh[o];
    }
    if (o == 0) {
        float m = -1e30f;
        for (int t = 0; t < T_P; ++t) m = fmaxf(m, att[t]);
        float e[T_P], s = 0.f;
        for (int t = 0; t < T_P; ++t) { e[t] = __expf(att[t] - m); s += e[t]; }
        float inv = 1.0f / s;
        for (int t = 0; t < T_P; ++t) P[t] = e[t] * inv;
    }
}

// per-chunk bucket histogram (LDS atomics only)
__global__ void hist_kernel(const int* __restrict__ dst, int* __restrict__ histo) {
    __shared__ int h[NB];
    int c = blockIdx.x;
    for (int i = threadIdx.x; i < NB; i += 256) h[i] = 0;
    __syncthreads();
    const int* de = dst + c * CE;
    for (int i = threadIdx.x; i < CE; i += 256)
        atomicAdd(&h[de[i] >> 8], 1);
    __syncthreads();
    for (int b = threadIdx.x; b < NB; b += 256) histo[b * NC + c] = h[b];
}

// per-bucket exclusive scan over chunks
__global__ void scan_bc_kernel(const int* __restrict__ histo, int* __restrict__ bp,
                               int* __restrict__ tot) {
    __shared__ int buf[NC];
    int b = blockIdx.x, t = threadIdx.x;
    int v = histo[b * NC + t];
    buf[t] = v;
    __syncthreads();
    for (int d = 1; d < NC; d <<= 1) {
        int u = (t >= d) ? buf[t - d] : 0;
        __syncthreads();
        buf[t] += u;
        __syncthreads();
    }
    bp[b * NC + t] = buf[t] - v;
    if (t == NC - 1) tot[b] = buf[t];
}

// exclusive scan over bucket totals -> start[], start[NB]=E
__global__ void scan_tot_kernel(const int* __restrict__ tot, int* __restrict__ start) {
    __shared__ int buf[512];
    int t = threadIdx.x;
    int v = (t < NB) ? tot[t] : 0;
    buf[t] = v;
    __syncthreads();
    for (int d = 1; d < 512; d <<= 1) {
        int u = (t >= d) ? buf[t - d] : 0;
        __syncthreads();
        buf[t] += u;
        __syncthreads();
    }
    if (t < NB) start[t] = buf[t] - v;
    if (t == NB - 1) start[NB] = buf[t];
}

// place edges grouped by bucket; LDS cursor atomics only
__global__ void scatter_kernel(const int* __restrict__ src, const int* __restrict__ dst,
                               const float* __restrict__ w, const int* __restrict__ bp,
                               const int* __restrict__ start, uint2* __restrict__ rec) {
    __shared__ int cur[NB];
    int c = blockIdx.x;
    for (int b = threadIdx.x; b < NB; b += 256) cur[b] = start[b] + bp[b * NC + c];
    __syncthreads();
    int e0 = c * CE;
    for (int i = threadIdx.x; i < CE; i += 256) {
        int e = e0 + i;
        int d = dst[e];
        int b = d >> 8;
        int pos = atomicAdd(&cur[b], 1);
        rec[pos] = make_uint2((unsigned)src[e] | ((unsigned)(d & 255) << 17),
                              __float_as_uint(w[e]));
    }
}

// per-(bucket,slice) degree accumulation in LDS
__global__ void deg_kernel(const uint2* __restrict__ rec, const int* __restrict__ start,
                           float* __restrict__ degp) {
    __shared__ float ldeg[NPB];
    int b = blockIdx.x / K_DEG, k = blockIdx.x % K_DEG;
    for (int i = threadIdx.x; i < NPB; i += 256) ldeg[i] = 0.f;
    __syncthreads();
    int s0 = start[b], cnt = start[b + 1] - s0;
    int a = s0 + (int)((long long)cnt * k / K_DEG);
    int z = s0 + (int)((long long)cnt * (k + 1) / K_DEG);
    for (int i = a + threadIdx.x; i < z; i += 256) {
        uint2 r = rec[i];
        atomicAdd(&ldeg[r.x >> 17], __uint_as_float(r.y));
    }
    __syncthreads();
    float* dp = degp + (size_t)k * NBP + (size_t)b * NPB;
    for (int i = threadIdx.x; i < NPB; i += 256) dp[i] = ldeg[i];
}

__global__ void dinv_kernel(const float* __restrict__ degp, float* __restrict__ dinv) {
    int i = blockIdx.x * 256 + threadIdx.x;
    if (i < NBP) {
        float d = 1.f;   // self-loop
        for (int k = 0; k < K_DEG; ++k) d += degp[(size_t)k * NBP + i];
        dinv[i] = rsqrtf(d);
    }
}

// per-(bucket,slice) aggregation: acc[dl][t] += w*dinv[s]*x[s,t] in LDS
__global__ void agg_kernel(const uint2* __restrict__ rec, const int* __restrict__ start,
                           const float* __restrict__ dinv, const float* __restrict__ x,
                           float* __restrict__ aggp) {
    __shared__ float acc[NPB][13];   // pad 13: coprime with 32 banks
    int b = blockIdx.x / K_AGG, k = blockIdx.x % K_AGG;
    for (int i = threadIdx.x; i < NPB * 13; i += 256) ((float*)acc)[i] = 0.f;
    __syncthreads();
    int s0 = start[b], cnt = start[b + 1] - s0;
    int a = s0 + (int)((long long)cnt * k / K_AGG);
    int z = s0 + (int)((long long)cnt * (k + 1) / K_AGG);
    for (int i = a + threadIdx.x; i < z; i += 256) {
        uint2 r = rec[i];
        int s  = r.x & 0x1FFFF;
        int dl = r.x >> 17;
        float coef = __uint_as_float(r.y) * dinv[s];
        const float4* xs = (const float4*)(x + (size_t)s * T_P);
        float4 x0 = xs[0], x1 = xs[1], x2 = xs[2];
        float* ar = acc[dl];
        atomicAdd(ar + 0,  coef * x0.x);
        atomicAdd(ar + 1,  coef * x0.y);
        atomicAdd(ar + 2,  coef * x0.z);
        atomicAdd(ar + 3,  coef * x0.w);
        atomicAdd(ar + 4,  coef * x1.x);
        atomicAdd(ar + 5,  coef * x1.y);
        atomicAdd(ar + 6,  coef * x1.z);
        atomicAdd(ar + 7,  coef * x1.w);
        atomicAdd(ar + 8,  coef * x2.x);
        atomicAdd(ar + 9,  coef * x2.y);
        atomicAdd(ar + 10, coef * x2.z);
        atomicAdd(ar + 11, coef * x2.w);
    }
    __syncthreads();
    float* ap = aggp + (size_t)k * NBP * T_P + (size_t)b * NPB * T_P;
    for (int i = threadIdx.x; i < NPB * T_P; i += 256) {
        int dl = i / T_P, t = i - dl * T_P;
        ap[i] = acc[dl][t];
    }
}

// fused: sum slices, self-loop, outer dinv, gates, attention, relu, head
__global__ void final_kernel(const float* __restrict__ x, const float* __restrict__ dinv,
                             const float* __restrict__ aggp, const float* __restrict__ P,
                             const float* __restrict__ head_w, const float* __restrict__ head_b,
                             float* __restrict__ out) {
    int tid = blockIdx.x * blockDim.x + threadIdx.x;
    int n = tid >> 5;
    int o = tid & 31;
    if (n >= N_NODES) return;
    float Az = P[16 + o], Bz = P[48 + o], Ah = P[80 + o], Bh = P[112 + o];
    float din = dinv[n];
    float h = 0.f;
#pragma unroll
    for (int t = 0; t < T_P; ++t) {
        float s = aggp[(size_t)n * T_P + t] + aggp[(size_t)NBP * T_P + (size_t)n * T_P + t];
        float a = din * (din * x[(size_t)n * T_P + t] + s);
        float oz = 1.f / (1.f + __expf(a * Az + Bz));          // 1 - sigmoid
        float v  = a * Ah + Bh;
        float th = 1.f - 2.f / (1.f + __expf(2.f * v));        // tanh
        h += P[t] * oz * th;
    }
    h = fmaxf(h, 0.f) * head_w[o];
#pragma unroll
    for (int m = 16; m > 0; m >>= 1) h += __shfl_xor(h, m, 32);
    if (o == 0) out[n] = h + head_b[0];
}

extern "C" void kernel_launch(void* const* d_in, const int* in_sizes, int n_in,
                              void* d_out, int out_size, void* d_ws, size_t ws_size,
                              hipStream_t stream) {
    const float* x    = (const float*)d_in[0];
    const int*   ei   = (const int*)d_in[1];
    const float* ew   = (const float*)d_in[2];
    const float* w_z  = (const float*)d_in[3];
    const float* b_z  = (const float*)d_in[4];
    const float* w_h  = (const float*)d_in[7];
    const float* b_h  = (const float*)d_in[8];
    const float* lw_z = (const float*)d_in[9];
    const float* lb_z = (const float*)d_in[10];
    const float* lw_h = (const float*)d_in[13];
    const float* lb_h = (const float*)d_in[14];
    const float* att  = (const float*)d_in[15];
    const float* hw   = (const float*)d_in[16];
    const float* hb   = (const float*)d_in[17];
    float* out = (float*)d_out;

    int*   wsi   = (int*)d_ws;
    float* P     = (float*)wsi;                 // 256
    int*   start = wsi + 256;                   // NB+1 (392)
    int*   tot   = wsi + 648;                   // 392
    int*   histo = wsi + 1040;                  // NB*NC
    int*   bp    = histo + NBP;                 // NB*NC (NBP == NB*NC here numerically? no)
    // NB*NC = 391*256 = 100096 == NBP — same number, reuse constant
    float* degp  = (float*)(bp + NB * NC);      // K_DEG*NBP
    float* dinv  = degp + (size_t)K_DEG * NBP;  // NBP
    uint2* rec   = (uint2*)(dinv + NBP);        // E
    float* aggp  = (float*)(rec + E_EDGES);     // K_AGG*NBP*T_P

    const int* src = ei;
    const int* dst = ei + E_EDGES;

    params_kernel<<<1, 64, 0, stream>>>(w_z, b_z, w_h, b_h, lw_z, lb_z, lw_h, lb_h, att, P);
    hist_kernel<<<NC, 256, 0, stream>>>(dst, histo);
    scan_bc_kernel<<<NB, NC, 0, stream>>>(histo, bp, tot);
    scan_tot_kernel<<<1, 512, 0, stream>>>(tot, start);
    scatter_kernel<<<NC, 256, 0, stream>>>(src, dst, ew, bp, start, rec);
    deg_kernel<<<NB * K_DEG, 256, 0, stream>>>(rec, start, degp);
    dinv_kernel<<<(NBP + 255) / 256, 256, 0, stream>>>(degp, dinv);
    agg_kernel<<<NB * K_AGG, 256, 0, stream>>>(rec, start, dinv, x, aggp);
    final_kernel<<<(N_NODES * C_H + 255) / 256, 256, 0, stream>>>(x, dinv, aggp, P, hw, hb, out);
}

// Round 4
// 485.144 us; speedup vs baseline: 1.0568x; 1.0568x over previous
//
#include <hip/hip_runtime.h>

#define N_NODES 100000
#define T_P 12
#define C_H 32
#define E_EDGES 3200000

#define NPB 256                 // nodes per bucket (dst>>8)
#define NB 391                  // ceil(N/256)
#define NBP (NB * NPB)          // padded node count = 100096
#define NC 256                  // edge chunks
#define CE 12500                // edges per chunk (NC*CE == E)
#define K_DEG 2
#define K_AGG 2

// ws layout (4B units), ~42.0 MB total:
//  P:256 | start:392 | tot:392 | histo:NB*NC | bp:NB*NC | degp:K_DEG*NBP | dinv:NBP
//  | y:NBP*T_P | rec:2*E (uint2) | aggp:K_AGG*NBP*T_P

__global__ void params_kernel(const float* __restrict__ wz, const float* __restrict__ bz,
                              const float* __restrict__ wh, const float* __restrict__ bh,
                              const float* __restrict__ lwz, const float* __restrict__ lbz,
                              const float* __restrict__ lwh, const float* __restrict__ lbh,
                              const float* __restrict__ att, float* __restrict__ P) {
    int o = threadIdx.x;
    if (o < C_H) {
        float az = 0.f, bzv = 0.f, ah = 0.f, bhv = 0.f;
        for (int c = 0; c < C_H; ++c) {
            float lz = lwz[o * 2 * C_H + c];
            float lh = lwh[o * 2 * C_H + c];
            az += wz[c] * lz;  bzv += bz[c] * lz;
            ah += wh[c] * lh;  bhv += bh[c] * lh;
        }
        P[16 + o]  = az;  P[48 + o]  = bzv + lbz[o];
        P[80 + o]  = ah;  P[112 + o] = bhv + lbh[o];
    }
    if (o == 0) {
        float m = -1e30f;
        for (int t = 0; t < T_P; ++t) m = fmaxf(m, att[t]);
        float e[T_P], s = 0.f;
        for (int t = 0; t < T_P; ++t) { e[t] = __expf(att[t] - m); s += e[t]; }
        float inv = 1.0f / s;
        for (int t = 0; t < T_P; ++t) P[t] = e[t] * inv;
    }
}

__global__ void hist_kernel(const int* __restrict__ dst, int* __restrict__ histo) {
    __shared__ int h[NB];
    int c = blockIdx.x;
    for (int i = threadIdx.x; i < NB; i += 1024) h[i] = 0;
    __syncthreads();
    const int* de = dst + c * CE;
    for (int i = threadIdx.x; i < CE; i += 1024)
        atomicAdd(&h[de[i] >> 8], 1);
    __syncthreads();
    for (int b = threadIdx.x; b < NB; b += 1024) histo[b * NC + c] = h[b];
}

__global__ void scan_bc_kernel(const int* __restrict__ histo, int* __restrict__ bp,
                               int* __restrict__ tot) {
    __shared__ int buf[NC];
    int b = blockIdx.x, t = threadIdx.x;
    int v = histo[b * NC + t];
    buf[t] = v;
    __syncthreads();
    for (int d = 1; d < NC; d <<= 1) {
        int u = (t >= d) ? buf[t - d] : 0;
        __syncthreads();
        buf[t] += u;
        __syncthreads();
    }
    bp[b * NC + t] = buf[t] - v;
    if (t == NC - 1) tot[b] = buf[t];
}

__global__ void scan_tot_kernel(const int* __restrict__ tot, int* __restrict__ start) {
    __shared__ int buf[512];
    int t = threadIdx.x;
    int v = (t < NB) ? tot[t] : 0;
    buf[t] = v;
    __syncthreads();
    for (int d = 1; d < 512; d <<= 1) {
        int u = (t >= d) ? buf[t - d] : 0;
        __syncthreads();
        buf[t] += u;
        __syncthreads();
    }
    if (t < NB) start[t] = buf[t] - v;
    if (t == NB - 1) start[NB] = buf[t];
}

__global__ void scatter_kernel(const int* __restrict__ src, const int* __restrict__ dst,
                               const float* __restrict__ w, const int* __restrict__ bp,
                               const int* __restrict__ start, uint2* __restrict__ rec) {
    __shared__ int cur[NB];
    int c = blockIdx.x;
    for (int b = threadIdx.x; b < NB; b += 1024) cur[b] = start[b] + bp[b * NC + c];
    __syncthreads();
    int e0 = c * CE;
    for (int i = threadIdx.x; i < CE; i += 1024) {
        int e = e0 + i;
        int d = dst[e];
        int b = d >> 8;
        int pos = atomicAdd(&cur[b], 1);
        rec[pos] = make_uint2((unsigned)src[e] | ((unsigned)(d & 255) << 17),
                              __float_as_uint(w[e]));
    }
}

__global__ void deg_kernel(const uint2* __restrict__ rec, const int* __restrict__ start,
                           float* __restrict__ degp) {
    __shared__ float ldeg[NPB];
    int b = blockIdx.x / K_DEG, k = blockIdx.x % K_DEG;
    for (int i = threadIdx.x; i < NPB; i += 1024) ldeg[i] = 0.f;
    __syncthreads();
    int s0 = start[b], cnt = start[b + 1] - s0;
    int a = s0 + (int)((long long)cnt * k / K_DEG);
    int z = s0 + (int)((long long)cnt * (k + 1) / K_DEG);
    for (int i = a + threadIdx.x; i < z; i += 1024) {
        uint2 r = rec[i];
        atomicAdd(&ldeg[r.x >> 17], __uint_as_float(r.y));
    }
    __syncthreads();
    float* dp = degp + (size_t)k * NBP + (size_t)b * NPB;
    for (int i = threadIdx.x; i < NPB; i += 1024) dp[i] = ldeg[i];
}

__global__ void dinv_kernel(const float* __restrict__ degp, float* __restrict__ dinv) {
    int i = blockIdx.x * 256 + threadIdx.x;
    if (i < NBP) {
        float d = 1.f;   // self-loop
        for (int k = 0; k < K_DEG; ++k) d += degp[(size_t)k * NBP + i];
        dinv[i] = rsqrtf(d);
    }
}

// y[n,t] = dinv[n] * x[n,t]  (streaming, coalesced)
__global__ void y_kernel(const float* __restrict__ x, const float* __restrict__ dinv,
                         float* __restrict__ y) {
    int i = blockIdx.x * 256 + threadIdx.x;
    if (i < N_NODES * T_P) y[i] = dinv[i / T_P] * x[i];
}

// acc[dl][t] += w * y[s,t] in LDS; one 48B gather per edge
__global__ void agg_kernel(const uint2* __restrict__ rec, const int* __restrict__ start,
                           const float* __restrict__ y, float* __restrict__ aggp) {
    __shared__ float acc[NPB][13];   // pad 13: coprime with 32 banks
    int b = blockIdx.x / K_AGG, k = blockIdx.x % K_AGG;
    for (int i = threadIdx.x; i < NPB * 13; i += 1024) ((float*)acc)[i] = 0.f;
    __syncthreads();
    int s0 = start[b], cnt = start[b + 1] - s0;
    int a = s0 + (int)((long long)cnt * k / K_AGG);
    int z = s0 + (int)((long long)cnt * (k + 1) / K_AGG);
    for (int i = a + threadIdx.x; i < z; i += 1024) {
        uint2 r = rec[i];
        int s  = r.x & 0x1FFFF;
        int dl = r.x >> 17;
        float coef = __uint_as_float(r.y);
        const float4* ys = (const float4*)(y + (size_t)s * T_P);
        float4 x0 = ys[0], x1 = ys[1], x2 = ys[2];
        float* ar = acc[dl];
        atomicAdd(ar + 0,  coef * x0.x);
        atomicAdd(ar + 1,  coef * x0.y);
        atomicAdd(ar + 2,  coef * x0.z);
        atomicAdd(ar + 3,  coef * x0.w);
        atomicAdd(ar + 4,  coef * x1.x);
        atomicAdd(ar + 5,  coef * x1.y);
        atomicAdd(ar + 6,  coef * x1.z);
        atomicAdd(ar + 7,  coef * x1.w);
        atomicAdd(ar + 8,  coef * x2.x);
        atomicAdd(ar + 9,  coef * x2.y);
        atomicAdd(ar + 10, coef * x2.z);
        atomicAdd(ar + 11, coef * x2.w);
    }
    __syncthreads();
    float* ap = aggp + (size_t)k * NBP * T_P + (size_t)b * NPB * T_P;
    for (int i = threadIdx.x; i < NPB * T_P; i += 1024) {
        int dl = i / T_P, t = i - dl * T_P;
        ap[i] = acc[dl][t];
    }
}

// a = dinv[n] * (y[n,t] + sum_k aggp[k][n][t]); gates; attention; relu; head
__global__ void final_kernel(const float* __restrict__ y, const float* __restrict__ dinv,
                             const float* __restrict__ aggp, const float* __restrict__ P,
                             const float* __restrict__ head_w, const float* __restrict__ head_b,
                             float* __restrict__ out) {
    int tid = blockIdx.x * blockDim.x + threadIdx.x;
    int n = tid >> 5;
    int o = tid & 31;
    if (n >= N_NODES) return;
    float Az = P[16 + o], Bz = P[48 + o], Ah = P[80 + o], Bh = P[112 + o];
    float din = dinv[n];
    float h = 0.f;
#pragma unroll
    for (int t = 0; t < T_P; ++t) {
        float s = y[(size_t)n * T_P + t]
                + aggp[(size_t)n * T_P + t]
                + aggp[(size_t)NBP * T_P + (size_t)n * T_P + t];
        float a = din * s;
        float oz = 1.f / (1.f + __expf(a * Az + Bz));          // 1 - sigmoid
        float v  = a * Ah + Bh;
        float th = 1.f - 2.f / (1.f + __expf(2.f * v));        // tanh
        h += P[t] * oz * th;
    }
    h = fmaxf(h, 0.f) * head_w[o];
#pragma unroll
    for (int m = 16; m > 0; m >>= 1) h += __shfl_xor(h, m, 32);
    if (o == 0) out[n] = h + head_b[0];
}

extern "C" void kernel_launch(void* const* d_in, const int* in_sizes, int n_in,
                              void* d_out, int out_size, void* d_ws, size_t ws_size,
                              hipStream_t stream) {
    const float* x    = (const float*)d_in[0];
    const int*   ei   = (const int*)d_in[1];
    const float* ew   = (const float*)d_in[2];
    const float* w_z  = (const float*)d_in[3];
    const float* b_z  = (const float*)d_in[4];
    const float* w_h  = (const float*)d_in[7];
    const float* b_h  = (const float*)d_in[8];
    const float* lw_z = (const float*)d_in[9];
    const float* lb_z = (const float*)d_in[10];
    const float* lw_h = (const float*)d_in[13];
    const float* lb_h = (const float*)d_in[14];
    const float* att  = (const float*)d_in[15];
    const float* hw   = (const float*)d_in[16];
    const float* hb   = (const float*)d_in[17];
    float* out = (float*)d_out;

    int*   wsi   = (int*)d_ws;
    float* P     = (float*)wsi;                 // 256
    int*   start = wsi + 256;                   // 392
    int*   tot   = wsi + 648;                   // 392
    int*   histo = wsi + 1040;                  // NB*NC = 100096
    int*   bp    = histo + NB * NC;             // NB*NC
    float* degp  = (float*)(bp + NB * NC);      // K_DEG*NBP
    float* dinv  = degp + (size_t)K_DEG * NBP;  // NBP
    float* y     = dinv + NBP;                  // NBP*T_P
    uint2* rec   = (uint2*)(y + (size_t)NBP * T_P);   // E  (offset is even -> 8B aligned)
    float* aggp  = (float*)(rec + E_EDGES);     // K_AGG*NBP*T_P

    const int* src = ei;
    const int* dst = ei + E_EDGES;

    params_kernel<<<1, 64, 0, stream>>>(w_z, b_z, w_h, b_h, lw_z, lb_z, lw_h, lb_h, att, P);
    hist_kernel<<<NC, 1024, 0, stream>>>(dst, histo);
    scan_bc_kernel<<<NB, NC, 0, stream>>>(histo, bp, tot);
    scan_tot_kernel<<<1, 512, 0, stream>>>(tot, start);
    scatter_kernel<<<NC, 1024, 0, stream>>>(src, dst, ew, bp, start, rec);
    deg_kernel<<<NB * K_DEG, 1024, 0, stream>>>(rec, start, degp);
    dinv_kernel<<<(NBP + 255) / 256, 256, 0, stream>>>(degp, dinv);
    y_kernel<<<(N_NODES * T_P + 255) / 256, 256, 0, stream>>>(x, dinv, y);
    agg_kernel<<<NB * K_AGG, 1024, 0, stream>>>(rec, start, y, aggp);
    final_kernel<<<(N_NODES * C_H + 255) / 256, 256, 0, stream>>>(y, dinv, aggp, P, hw, hb, out);
}

// Round 5
// 465.559 us; speedup vs baseline: 1.1013x; 1.0421x over previous
//
#include <hip/hip_runtime.h>

#define N_NODES 100000
#define T_P 12
#define C_H 32
#define E_EDGES 3200000

#define NPB 256                 // nodes per bucket (dst>>8)
#define NB 391                  // ceil(N/256)
#define NBP (NB * NPB)          // padded node count = 100096
#define NC 256                  // edge chunks
#define CE 12500                // edges per chunk (NC*CE == E)
#define K_DEG 8
#define K_AGG 2

// ws layout (4B units), ~42.4 MB total:
//  P:256 | start:392 | tot:392 | histo:NB*NC | bp:NB*NC | degp:K_DEG*NBP | dinv:NBP
//  | y:NBP*T_P | rec:2*E (uint2) | aggp:K_AGG*NBP*T_P

__global__ void params_kernel(const float* __restrict__ wz, const float* __restrict__ bz,
                              const float* __restrict__ wh, const float* __restrict__ bh,
                              const float* __restrict__ lwz, const float* __restrict__ lbz,
                              const float* __restrict__ lwh, const float* __restrict__ lbh,
                              const float* __restrict__ att, float* __restrict__ P) {
    int o = threadIdx.x;
    if (o < C_H) {
        float az = 0.f, bzv = 0.f, ah = 0.f, bhv = 0.f;
        for (int c = 0; c < C_H; ++c) {
            float lz = lwz[o * 2 * C_H + c];
            float lh = lwh[o * 2 * C_H + c];
            az += wz[c] * lz;  bzv += bz[c] * lz;
            ah += wh[c] * lh;  bhv += bh[c] * lh;
        }
        P[16 + o]  = az;  P[48 + o]  = bzv + lbz[o];
        P[80 + o]  = ah;  P[112 + o] = bhv + lbh[o];
    }
    if (o == 0) {
        float m = -1e30f;
        for (int t = 0; t < T_P; ++t) m = fmaxf(m, att[t]);
        float e[T_P], s = 0.f;
        for (int t = 0; t < T_P; ++t) { e[t] = __expf(att[t] - m); s += e[t]; }
        float inv = 1.0f / s;
        for (int t = 0; t < T_P; ++t) P[t] = e[t] * inv;
    }
}

__global__ void hist_kernel(const int* __restrict__ dst, int* __restrict__ histo) {
    __shared__ int h[NB];
    int c = blockIdx.x;
    for (int i = threadIdx.x; i < NB; i += 1024) h[i] = 0;
    __syncthreads();
    const int* de = dst + c * CE;
    for (int i = threadIdx.x; i < CE; i += 1024)
        atomicAdd(&h[de[i] >> 8], 1);
    __syncthreads();
    for (int b = threadIdx.x; b < NB; b += 1024) histo[b * NC + c] = h[b];
}

__global__ void scan_bc_kernel(const int* __restrict__ histo, int* __restrict__ bp,
                               int* __restrict__ tot) {
    __shared__ int buf[NC];
    int b = blockIdx.x, t = threadIdx.x;
    int v = histo[b * NC + t];
    buf[t] = v;
    __syncthreads();
    for (int d = 1; d < NC; d <<= 1) {
        int u = (t >= d) ? buf[t - d] : 0;
        __syncthreads();
        buf[t] += u;
        __syncthreads();
    }
    bp[b * NC + t] = buf[t] - v;
    if (t == NC - 1) tot[b] = buf[t];
}

__global__ void scan_tot_kernel(const int* __restrict__ tot, int* __restrict__ start) {
    __shared__ int buf[512];
    int t = threadIdx.x;
    int v = (t < NB) ? tot[t] : 0;
    buf[t] = v;
    __syncthreads();
    for (int d = 1; d < 512; d <<= 1) {
        int u = (t >= d) ? buf[t - d] : 0;
        __syncthreads();
        buf[t] += u;
        __syncthreads();
    }
    if (t < NB) start[t] = buf[t] - v;
    if (t == NB - 1) start[NB] = buf[t];
}

__global__ void scatter_kernel(const int* __restrict__ src, const int* __restrict__ dst,
                               const float* __restrict__ w, const int* __restrict__ bp,
                               const int* __restrict__ start, uint2* __restrict__ rec) {
    __shared__ int cur[NB];
    int c = blockIdx.x;
    for (int b = threadIdx.x; b < NB; b += 1024) cur[b] = start[b] + bp[b * NC + c];
    __syncthreads();
    int e0 = c * CE;
    for (int i = threadIdx.x; i < CE; i += 1024) {
        int e = e0 + i;
        int d = dst[e];
        int b = d >> 8;
        int pos = atomicAdd(&cur[b], 1);
        rec[pos] = make_uint2((unsigned)src[e] | ((unsigned)(d & 255) << 17),
                              __float_as_uint(w[e]));
    }
}

__global__ void deg_kernel(const uint2* __restrict__ rec, const int* __restrict__ start,
                           float* __restrict__ degp) {
    __shared__ float ldeg[NPB];
    int b = blockIdx.x / K_DEG, k = blockIdx.x % K_DEG;
    for (int i = threadIdx.x; i < NPB; i += 256) ldeg[i] = 0.f;
    __syncthreads();
    int s0 = start[b], cnt = start[b + 1] - s0;
    int a = s0 + (int)((long long)cnt * k / K_DEG);
    int z = s0 + (int)((long long)cnt * (k + 1) / K_DEG);
    for (int i = a + threadIdx.x; i < z; i += 256) {
        uint2 r = rec[i];
        atomicAdd(&ldeg[r.x >> 17], __uint_as_float(r.y));
    }
    __syncthreads();
    float* dp = degp + (size_t)k * NBP + (size_t)b * NPB;
    for (int i = threadIdx.x; i < NPB; i += 256) dp[i] = ldeg[i];
}

// dinv[n] = rsqrt(1 + sum_k degp[k][n]);  y[n,t] = dinv[n]*x[n,t]
__global__ void dinvy_kernel(const float* __restrict__ degp, const float* __restrict__ x,
                             float* __restrict__ dinv, float* __restrict__ y) {
    int n = blockIdx.x * 256 + threadIdx.x;
    if (n >= NBP) return;
    if (n >= N_NODES) { dinv[n] = 0.f; return; }
    float d = 1.f;   // self-loop
#pragma unroll
    for (int k = 0; k < K_DEG; ++k) d += degp[(size_t)k * NBP + n];
    float di = rsqrtf(d);
    dinv[n] = di;
    const float4* xr = (const float4*)(x + (size_t)n * T_P);
    float4 a0 = xr[0], a1 = xr[1], a2 = xr[2];
    a0.x *= di; a0.y *= di; a0.z *= di; a0.w *= di;
    a1.x *= di; a1.y *= di; a1.z *= di; a1.w *= di;
    a2.x *= di; a2.y *= di; a2.z *= di; a2.w *= di;
    float4* yr = (float4*)(y + (size_t)n * T_P);
    yr[0] = a0; yr[1] = a1; yr[2] = a2;
}

// 4 lanes per edge: lane c loads the 12B chunk c of y[s] (dwordx3, line-shared)
__global__ void agg_kernel(const uint2* __restrict__ rec, const int* __restrict__ start,
                           const float* __restrict__ y, float* __restrict__ aggp) {
    __shared__ float acc[NPB][13];   // pad 13: coprime with 32 banks
    int b = blockIdx.x >> 1, k = blockIdx.x & 1;
    for (int i = threadIdx.x; i < NPB * 13; i += 512) ((float*)acc)[i] = 0.f;
    __syncthreads();
    int s0 = start[b], cnt = start[b + 1] - s0;
    int a = s0 + (int)((long long)cnt * k / K_AGG);
    int z = s0 + (int)((long long)cnt * (k + 1) / K_AGG);
    int c = threadIdx.x & 3;            // chunk within row
    int co = c * 3;                     // t-offset of chunk
    for (int i = a + (threadIdx.x >> 2); i < z; i += 128) {
        uint2 r = rec[i];               // 4 lanes same addr -> broadcast
        int s  = r.x & 0x1FFFF;
        int dl = r.x >> 17;
        float w = __uint_as_float(r.y);
        const float* row = y + (size_t)s * T_P + co;
        float v0 = row[0], v1 = row[1], v2 = row[2];   // merges to dwordx3
        float* ar = acc[dl] + co;
        atomicAdd(ar + 0, w * v0);
        atomicAdd(ar + 1, w * v1);
        atomicAdd(ar + 2, w * v2);
    }
    __syncthreads();
    float* ap = aggp + (size_t)k * NBP * T_P + (size_t)b * NPB * T_P;
    for (int i = threadIdx.x; i < NPB * T_P; i += 512) {
        int dl = i / T_P, t = i - dl * T_P;
        ap[i] = acc[dl][t];
    }
}

__global__ void final_kernel(const float* __restrict__ y, const float* __restrict__ dinv,
                             const float* __restrict__ aggp, const float* __restrict__ P,
                             const float* __restrict__ head_w, const float* __restrict__ head_b,
                             float* __restrict__ out) {
    int tid = blockIdx.x * blockDim.x + threadIdx.x;
    int n = tid >> 5;
    int o = tid & 31;
    if (n >= N_NODES) return;
    float Az = P[16 + o], Bz = P[48 + o], Ah = P[80 + o], Bh = P[112 + o];
    float din = dinv[n];
    float h = 0.f;
#pragma unroll
    for (int t = 0; t < T_P; ++t) {
        float s = y[(size_t)n * T_P + t]
                + aggp[(size_t)n * T_P + t]
                + aggp[(size_t)NBP * T_P + (size_t)n * T_P + t];
        float a = din * s;
        float oz = 1.f / (1.f + __expf(a * Az + Bz));          // 1 - sigmoid
        float v  = a * Ah + Bh;
        float th = 1.f - 2.f / (1.f + __expf(2.f * v));        // tanh
        h += P[t] * oz * th;
    }
    h = fmaxf(h, 0.f) * head_w[o];
#pragma unroll
    for (int m = 16; m > 0; m >>= 1) h += __shfl_xor(h, m, 32);
    if (o == 0) out[n] = h + head_b[0];
}

extern "C" void kernel_launch(void* const* d_in, const int* in_sizes, int n_in,
                              void* d_out, int out_size, void* d_ws, size_t ws_size,
                              hipStream_t stream) {
    const float* x    = (const float*)d_in[0];
    const int*   ei   = (const int*)d_in[1];
    const float* ew   = (const float*)d_in[2];
    const float* w_z  = (const float*)d_in[3];
    const float* b_z  = (const float*)d_in[4];
    const float* w_h  = (const float*)d_in[7];
    const float* b_h  = (const float*)d_in[8];
    const float* lw_z = (const float*)d_in[9];
    const float* lb_z = (const float*)d_in[10];
    const float* lw_h = (const float*)d_in[13];
    const float* lb_h = (const float*)d_in[14];
    const float* att  = (const float*)d_in[15];
    const float* hw   = (const float*)d_in[16];
    const float* hb   = (const float*)d_in[17];
    float* out = (float*)d_out;

    int*   wsi   = (int*)d_ws;
    float* P     = (float*)wsi;                 // 256
    int*   start = wsi + 256;                   // 392
    int*   tot   = wsi + 648;                   // 392
    int*   histo = wsi + 1040;                  // NB*NC
    int*   bp    = histo + NB * NC;             // NB*NC
    float* degp  = (float*)(bp + NB * NC);      // K_DEG*NBP
    float* dinv  = degp + (size_t)K_DEG * NBP;  // NBP
    float* y     = dinv + NBP;                  // NBP*T_P
    uint2* rec   = (uint2*)(y + (size_t)NBP * T_P);   // E (8B-aligned offset)
    float* aggp  = (float*)(rec + E_EDGES);     // K_AGG*NBP*T_P

    const int* src = ei;
    const int* dst = ei + E_EDGES;

    params_kernel<<<1, 64, 0, stream>>>(w_z, b_z, w_h, b_h, lw_z, lb_z, lw_h, lb_h, att, P);
    hist_kernel<<<NC, 1024, 0, stream>>>(dst, histo);
    scan_bc_kernel<<<NB, NC, 0, stream>>>(histo, bp, tot);
    scan_tot_kernel<<<1, 512, 0, stream>>>(tot, start);
    scatter_kernel<<<NC, 1024, 0, stream>>>(src, dst, ew, bp, start, rec);
    deg_kernel<<<NB * K_DEG, 256, 0, stream>>>(rec, start, degp);
    dinvy_kernel<<<(NBP + 255) / 256, 256, 0, stream>>>(degp, x, dinv, y);
    agg_kernel<<<NB * K_AGG, 512, 0, stream>>>(rec, start, y, aggp);
    final_kernel<<<(N_NODES * C_H + 255) / 256, 256, 0, stream>>>(y, dinv, aggp, P, hw, hb, out);
}